// Round 9
// baseline (50.970 us; speedup 1.0000x reference)
//
#include <hip/hip_runtime.h>

// Problem dims (fixed by the reference)
#define LW   16      // chars per word (max)
#define GD   300     // glove dim
#define CEM  64      // char emb dim
#define OD   100     // out dim of conv/linear
#define NCH  128     // char vocab
#define NW   (32 * 512)   // 16384 words

// d_ws layout (floats):
//   [0     .. 12800)  T[128][100]   T[ch][o] = sum_e ce[ch][e] * Wc[e][o]
//   [12800 .. 12900)  c[100]
//   [12900 .. 12928)  pad (junk-lane bias reads in fused touch up to 12927)
// needs 12928 floats = 51.7 KB of d_ws.

// One block per char, 256 threads (4 waves). All global reads coalesced:
//   phase A: lane = e  -> conv_w[j*64+lane] (256B)  -> shfl-reduce -> U[j]
//   phase B: lane = j2 -> lin_w[o*100+2*lane] float2 (400B) -> shfl-reduce -> T[ch][o]
// Block 0 also computes c[o] = lin_b[o] + lin_w_row_o . conv_b.
__global__ __launch_bounds__(256) void precompute_T(
        const float* __restrict__ char_table, const float* __restrict__ conv_w,
        const float* __restrict__ conv_b,     const float* __restrict__ lin_w,
        const float* __restrict__ lin_b,      float* __restrict__ ws) {
    __shared__ float ceS[CEM];
    __shared__ float U[OD];
    const int tid  = threadIdx.x;
    const int wave = tid >> 6;
    const int lane = tid & 63;
    const int ch   = blockIdx.x;

    if (tid < CEM) ceS[tid] = char_table[ch * CEM + tid];
    __syncthreads();

    // ---- phase A: U[j], 25 j's per wave ----
    #pragma unroll 5
    for (int i = 0; i < 25; ++i) {
        const int j = wave * 25 + i;
        float p = conv_w[j * CEM + lane] * ceS[lane];   // coalesced 256B
        #pragma unroll
        for (int m = 32; m >= 1; m >>= 1) p += __shfl_xor(p, m);
        if (lane == 0) U[j] = p;
    }
    __syncthreads();

    // ---- phase B: T[ch][o], 25 o's per wave ----
    const bool actl = lane < OD / 2;                    // lanes 0..49
    #pragma unroll 5
    for (int i = 0; i < 25; ++i) {
        const int o = wave * 25 + i;
        float p = 0.f;
        if (actl) {
            const float2 w2 = ((const float2*)(lin_w + o * OD))[lane]; // coalesced 400B
            const float2 u2 = ((const float2*)U)[lane];
            p = fmaf(w2.x, u2.x, w2.y * u2.y);
        }
        #pragma unroll
        for (int m = 32; m >= 1; m >>= 1) p += __shfl_xor(p, m);
        if (lane == 0) ws[ch * OD + o] = p;
    }

    // ---- bias (block 0 only) ----
    if (ch == 0) {
        #pragma unroll 5
        for (int i = 0; i < 25; ++i) {
            const int o = wave * 25 + i;
            float p = 0.f;
            if (actl) {
                const float2 w2 = ((const float2*)(lin_w + o * OD))[lane];
                const float2 b2 = ((const float2*)conv_b)[lane];
                p = fmaf(w2.x, b2.x, w2.y * b2.y);
            }
            #pragma unroll
            for (int m = 32; m >= 1; m >>= 1) p += __shfl_xor(p, m);
            if (lane == 0) ws[NCH * OD + o] = p + lin_b[o];
        }
    }
}

// ---- fused_embed: R5 verbatim (known-good, 22.3us build). One wave per word. ----
__global__ __launch_bounds__(256) void fused_embed(
        const int*   __restrict__ word_tokens,
        const int*   __restrict__ char_ids,
        const int*   __restrict__ char_lens,
        const float* __restrict__ glove,
        const float* __restrict__ ws,
        float*       __restrict__ out) {
    const int wave = threadIdx.x >> 6;
    const int lane = threadIdx.x & 63;
    const int word = blockIdx.x * 4 + wave;

    const int tok = word_tokens[word];              // wave-uniform
    const int len = char_lens[word];                // wave-uniform, >= 1

    const int4* cid4 = (const int4*)(char_ids + (size_t)word * LW);
    const int4 i0 = cid4[0], i1 = cid4[1], i2 = cid4[2], i3 = cid4[3];

    // glove passthrough: 75 float4, coalesced
    const float4* g4 = (const float4*)(glove + (size_t)tok * GD);
    float4 g0 = g4[lane];
    float4 g1;
    const bool tail = lane < (GD / 4 - 64);         // lanes 0..10
    if (tail) g1 = g4[64 + lane];
    float4* d4 = (float4*)(out + (size_t)word * (GD + OD));
    d4[lane] = g0;
    if (tail) d4[64 + lane] = g1;

    // bias (load early, hides under gather)
    const float cl = ws[NCH * OD + lane];                          // c[lane]
    const bool hi = lane < (OD - 64);                              // lanes 0..35
    const float chv = ws[NCH * OD + 64 + lane];                    // junk if !hi, masked later
    float acc0 = 0.f, acc1 = 0.f;

#define CGROUP(iv, base)                                                   \
    {                                                                      \
        const float* t0 = ws + (iv).x * OD;                                \
        const float* t1 = ws + (iv).y * OD;                                \
        const float* t2 = ws + (iv).z * OD;                                \
        const float* t3 = ws + (iv).w * OD;                                \
        float v0 = t0[lane], w0 = t0[64 + lane];                           \
        float v1 = t1[lane], w1 = t1[64 + lane];                           \
        float v2 = t2[lane], w2 = t2[64 + lane];                           \
        float v3 = t3[lane], w3 = t3[64 + lane];                           \
        acc0 += ((base) + 0 < len) ? v0 : 0.f;                             \
        acc1 += ((base) + 0 < len) ? w0 : 0.f;                             \
        acc0 += ((base) + 1 < len) ? v1 : 0.f;                             \
        acc1 += ((base) + 1 < len) ? w1 : 0.f;                             \
        acc0 += ((base) + 2 < len) ? v2 : 0.f;                             \
        acc1 += ((base) + 2 < len) ? w2 : 0.f;                             \
        acc0 += ((base) + 3 < len) ? v3 : 0.f;                             \
        acc1 += ((base) + 3 < len) ? w3 : 0.f;                             \
    }

    CGROUP(i0, 0)                       // len >= 1 always
    if (len > 4)  CGROUP(i1, 4)
    if (len > 8)  CGROUP(i2, 8)
    if (len > 12) CGROUP(i3, 12)
#undef CGROUP

    const float inv = 1.f / (float)len;
    float* co = out + (size_t)word * (GD + OD) + GD;
    co[lane] = fmaf(acc0, inv, cl);
    if (hi) co[64 + lane] = fmaf(acc1, inv, chv);
}

extern "C" void kernel_launch(void* const* d_in, const int* in_sizes, int n_in,
                              void* d_out, int out_size, void* d_ws, size_t ws_size,
                              hipStream_t stream) {
    const int*   word_tokens = (const int*)  d_in[0];
    const int*   char_ids    = (const int*)  d_in[1];
    const int*   char_lens   = (const int*)  d_in[2];
    const float* glove       = (const float*)d_in[3];
    const float* char_table  = (const float*)d_in[4];
    const float* conv_w      = (const float*)d_in[5];
    const float* conv_b      = (const float*)d_in[6];
    const float* lin_w       = (const float*)d_in[7];
    const float* lin_b       = (const float*)d_in[8];
    float* out = (float*)d_out;
    float* ws  = (float*)d_ws;   // needs 12928 floats ~= 51.7 KB

    precompute_T<<<NCH, 256, 0, stream>>>(char_table, conv_w, conv_b, lin_w, lin_b, ws);

    fused_embed<<<NW / 4, 256, 0, stream>>>(
        word_tokens, char_ids, char_lens, glove, ws, out);
}

// Round 11
// 21.798 us; speedup vs baseline: 2.3383x; 2.3383x over previous
//
#include <hip/hip_runtime.h>

// Problem dims (fixed by the reference)
#define LW   16      // chars per word (max)
#define GD   300     // glove dim
#define CEM  64      // char emb dim
#define OD   100     // out dim of conv/linear
#define NCH  128     // char vocab
#define NW   (32 * 512)   // 16384 words

// d_ws layout (floats):
//   [0     .. 12800)  T[128][100]   T[ch][o] = sum_e ce[ch][e] * Wc[e][o]
//   [12800 .. 12900)  c[100]
//   [12900 .. 12928)  pad (junk-lane bias reads in k_char touch up to 12927)
// needs 12928 floats = 51.7 KB of d_ws.

// K1: blocks 0..127 run the R5 precompute body (ch = blockIdx); blocks 128..
// copy glove rows for 4 words each (wave = word). The precompute's ~4us of
// latency-bound work hides under ~8us of glove streaming on the other blocks.
__global__ __launch_bounds__(256) void k_pre_glove(
        const int*   __restrict__ word_tokens,
        const float* __restrict__ glove,
        const float* __restrict__ char_table,
        const float* __restrict__ conv_w,
        const float* __restrict__ conv_b,
        const float* __restrict__ lin_w,
        const float* __restrict__ lin_b,
        float* __restrict__ ws,
        float* __restrict__ out) {
    if (blockIdx.x < NCH) {
        // ---- R5 precompute_T body (verbatim logic; threads 128..255 idle) ----
        __shared__ float ceS[CEM];
        __shared__ float U[OD];
        const int t  = threadIdx.x;
        const int ch = blockIdx.x;

        if (t < CEM) ceS[t] = char_table[ch * CEM + t];
        __syncthreads();

        if (t < OD) {
            const float* cw = conv_w + t * CEM;
            float a0 = 0.f, a1 = 0.f, a2 = 0.f, a3 = 0.f;
            #pragma unroll
            for (int e = 0; e < CEM; e += 4) {
                a0 = fmaf(cw[e + 0], ceS[e + 0], a0);
                a1 = fmaf(cw[e + 1], ceS[e + 1], a1);
                a2 = fmaf(cw[e + 2], ceS[e + 2], a2);
                a3 = fmaf(cw[e + 3], ceS[e + 3], a3);
            }
            U[t] = (a0 + a1) + (a2 + a3);
        }
        __syncthreads();

        if (t < OD) {
            const float* lw = lin_w + t * OD;
            float a0 = 0.f, a1 = 0.f, a2 = 0.f, a3 = 0.f;
            #pragma unroll 5
            for (int j = 0; j < OD; j += 4) {
                a0 = fmaf(lw[j + 0], U[j + 0], a0);
                a1 = fmaf(lw[j + 1], U[j + 1], a1);
                a2 = fmaf(lw[j + 2], U[j + 2], a2);
                a3 = fmaf(lw[j + 3], U[j + 3], a3);
            }
            ws[ch * OD + t] = (a0 + a1) + (a2 + a3);

            if (ch == 0) {
                float b0 = lin_b[t], b1 = 0.f, b2 = 0.f, b3 = 0.f;
                #pragma unroll 5
                for (int j = 0; j < OD; j += 4) {
                    b0 = fmaf(lw[j + 0], conv_b[j + 0], b0);
                    b1 = fmaf(lw[j + 1], conv_b[j + 1], b1);
                    b2 = fmaf(lw[j + 2], conv_b[j + 2], b2);
                    b3 = fmaf(lw[j + 3], conv_b[j + 3], b3);
                }
                ws[NCH * OD + t] = (b0 + b1) + (b2 + b3);
            }
        }
    } else {
        // ---- glove copy: wave = word, 75 float4 per word ----
        const int wave = threadIdx.x >> 6;
        const int lane = threadIdx.x & 63;
        const int word = (blockIdx.x - NCH) * 4 + wave;

        const int tok = word_tokens[word];              // wave-uniform
        const float4* g4 = (const float4*)(glove + (size_t)tok * GD);
        float4 g0 = g4[lane];
        float4 g1;
        const bool tail = lane < (GD / 4 - 64);         // lanes 0..10
        if (tail) g1 = g4[64 + lane];

        float4* d4 = (float4*)(out + (size_t)word * (GD + OD));
        d4[lane] = g0;
        if (tail) d4[64 + lane] = g1;
    }
}

// K2: char path per wave (R5's fused minus the glove part).
__global__ __launch_bounds__(256) void k_char(
        const int*   __restrict__ char_ids,
        const int*   __restrict__ char_lens,
        const float* __restrict__ ws,
        float*       __restrict__ out) {
    const int wave = threadIdx.x >> 6;
    const int lane = threadIdx.x & 63;
    const int word = blockIdx.x * 4 + wave;

    const int len = char_lens[word];                // wave-uniform, >= 1

    const int4* cid4 = (const int4*)(char_ids + (size_t)word * LW);
    const int4 i0 = cid4[0], i1 = cid4[1], i2 = cid4[2], i3 = cid4[3];

    // bias (load early, hides under gather)
    const float cl = ws[NCH * OD + lane];                          // c[lane]
    const bool hi = lane < (OD - 64);                              // lanes 0..35
    const float chv = ws[NCH * OD + 64 + lane];                    // junk if !hi, masked later
    float acc0 = 0.f, acc1 = 0.f;

#define CGROUP(iv, base)                                                   \
    {                                                                      \
        const float* t0 = ws + (iv).x * OD;                                \
        const float* t1 = ws + (iv).y * OD;                                \
        const float* t2 = ws + (iv).z * OD;                                \
        const float* t3 = ws + (iv).w * OD;                                \
        float v0 = t0[lane], w0 = t0[64 + lane];                           \
        float v1 = t1[lane], w1 = t1[64 + lane];                           \
        float v2 = t2[lane], w2 = t2[64 + lane];                           \
        float v3 = t3[lane], w3 = t3[64 + lane];                           \
        acc0 += ((base) + 0 < len) ? v0 : 0.f;                             \
        acc1 += ((base) + 0 < len) ? w0 : 0.f;                             \
        acc0 += ((base) + 1 < len) ? v1 : 0.f;                             \
        acc1 += ((base) + 1 < len) ? w1 : 0.f;                             \
        acc0 += ((base) + 2 < len) ? v2 : 0.f;                             \
        acc1 += ((base) + 2 < len) ? w2 : 0.f;                             \
        acc0 += ((base) + 3 < len) ? v3 : 0.f;                             \
        acc1 += ((base) + 3 < len) ? w3 : 0.f;                             \
    }

    CGROUP(i0, 0)                       // len >= 1 always
    if (len > 4)  CGROUP(i1, 4)
    if (len > 8)  CGROUP(i2, 8)
    if (len > 12) CGROUP(i3, 12)
#undef CGROUP

    const float inv = 1.f / (float)len;
    float* co = out + (size_t)word * (GD + OD) + GD;
    co[lane] = fmaf(acc0, inv, cl);
    if (hi) co[64 + lane] = fmaf(acc1, inv, chv);
}

extern "C" void kernel_launch(void* const* d_in, const int* in_sizes, int n_in,
                              void* d_out, int out_size, void* d_ws, size_t ws_size,
                              hipStream_t stream) {
    const int*   word_tokens = (const int*)  d_in[0];
    const int*   char_ids    = (const int*)  d_in[1];
    const int*   char_lens   = (const int*)  d_in[2];
    const float* glove       = (const float*)d_in[3];
    const float* char_table  = (const float*)d_in[4];
    const float* conv_w      = (const float*)d_in[5];
    const float* conv_b      = (const float*)d_in[6];
    const float* lin_w       = (const float*)d_in[7];
    const float* lin_b       = (const float*)d_in[8];
    float* out = (float*)d_out;
    float* ws  = (float*)d_ws;   // needs 12928 floats ~= 51.7 KB

    k_pre_glove<<<NCH + NW / 4, 256, 0, stream>>>(
        word_tokens, glove, char_table, conv_w, conv_b, lin_w, lin_b, ws, out);

    k_char<<<NW / 4, 256, 0, stream>>>(char_ids, char_lens, ws, out);
}